// Round 1
// baseline (409.037 us; speedup 1.0000x reference)
//
#include <hip/hip_runtime.h>
#include <math.h>

#define HW 512
#define LOG2HW 9
#define NIMG 96      // N*C = 32*3
#define NBANDS 16

__device__ __forceinline__ unsigned bitrev9(unsigned x) {
    return __brev(x) >> (32 - LOG2HW);
}

// In-LDS 512-point radix-2 DIT FFT. Expects data already loaded in
// bit-reversed order into re/im. 256 threads, one butterfly each per stage.
// Caller must __syncthreads() after the bit-reversed load.
__device__ __forceinline__ void fft512(float* re, float* im, int t) {
    #pragma unroll
    for (int s = 1; s <= LOG2HW; ++s) {
        const int half = 1 << (s - 1);
        const int grp  = t >> (s - 1);
        const int pos  = t & (half - 1);
        const int i1   = (grp << s) + pos;
        const int i2   = i1 + half;
        const float ang = -3.14159265358979323846f * (float)pos / (float)half;
        float sn, cs;
        __sincosf(ang, &sn, &cs);
        const float xr = re[i2], xi = im[i2];
        const float tr = cs * xr - sn * xi;
        const float ti = cs * xi + sn * xr;
        const float ur = re[i1], ui = im[i1];
        re[i1] = ur + tr; im[i1] = ui + ti;
        re[i2] = ur - tr; im[i2] = ui - ti;
        __syncthreads();
    }
}

// wmap[k1*512+k2] = sum_b bw[b] * mask[b][(k1+256)%512][(k2+256)%512]
// (the index shift implements fftshift so later kernels work in natural
//  unshifted FFT frequency order)
__global__ void wmap_kernel(const float* __restrict__ bw,
                            const float* __restrict__ masks,
                            float* __restrict__ wmap) {
    int idx = blockIdx.x * blockDim.x + threadIdx.x;
    if (idx >= HW * HW) return;
    int k1 = idx >> LOG2HW, k2 = idx & (HW - 1);
    int p1 = (k1 + HW / 2) & (HW - 1);
    int p2 = (k2 + HW / 2) & (HW - 1);
    int off = p1 * HW + p2;
    float s = 0.f;
    #pragma unroll
    for (int b = 0; b < NBANDS; ++b)
        s += bw[b] * masks[b * HW * HW + off];
    wmap[idx] = s;
}

// One block per (image-in-chunk, row): err = pred - gt, row FFT, write
// complex row to fdata (chunk-local image index).
__global__ __launch_bounds__(256)
void rowfft_kernel(const float* __restrict__ pred,
                   const float* __restrict__ gt,
                   float2* __restrict__ fdata, int img0) {
    __shared__ float re[HW], im[HW];
    const int limg = blockIdx.y;
    const int img  = img0 + limg;
    const int row  = blockIdx.x;
    const int t    = threadIdx.x;

    const size_t base = ((size_t)img * HW + row) * HW;
    const float* p = pred + base;
    const float* g = gt + base;

    #pragma unroll
    for (int i = t; i < HW; i += 256) {
        float v = p[i] - g[i];
        unsigned r = bitrev9(i);
        re[r] = v; im[r] = 0.f;
    }
    __syncthreads();
    fft512(re, im, t);

    float2* out = fdata + ((size_t)limg * HW + row) * HW;
    #pragma unroll
    for (int i = t; i < HW; i += 256)
        out[i] = make_float2(re[i], im[i]);
}

// One block per (image-in-chunk, column): column FFT, power * wmap,
// block reduction -> partials[(img0+limg)*512 + col]. Deterministic.
__global__ __launch_bounds__(256)
void colfft_kernel(const float2* __restrict__ fdata,
                   const float* __restrict__ wmap,
                   float* __restrict__ partials, int img0) {
    __shared__ float re[HW], im[HW];
    __shared__ float red[256];
    const int limg = blockIdx.y;
    const int col  = blockIdx.x;
    const int t    = threadIdx.x;

    const float2* in = fdata + (size_t)limg * HW * HW + col;
    #pragma unroll
    for (int i = t; i < HW; i += 256) {
        float2 v = in[(size_t)i * HW];
        unsigned r = bitrev9(i);
        re[r] = v.x; im[r] = v.y;
    }
    __syncthreads();
    fft512(re, im, t);

    // ortho norm: F /= sqrt(H*W)=512  =>  |F|^2 /= 262144
    const float inv = 1.0f / (512.0f * 512.0f);
    float acc = 0.f;
    #pragma unroll
    for (int i = t; i < HW; i += 256) {
        float pw = (re[i] * re[i] + im[i] * im[i]) * inv;
        acc += pw * wmap[i * HW + col];
    }
    red[t] = acc;
    __syncthreads();
    #pragma unroll
    for (int s = 128; s > 0; s >>= 1) {
        if (t < s) red[t] += red[t + s];
        __syncthreads();
    }
    if (t == 0)
        partials[(size_t)(img0 + limg) * HW + col] = red[0];
}

__global__ void final_reduce(const float* __restrict__ partials,
                             float* __restrict__ out) {
    __shared__ float red[256];
    const int t = threadIdx.x;
    float acc = 0.f;
    for (int i = t; i < NIMG * HW; i += 256) acc += partials[i];
    red[t] = acc;
    __syncthreads();
    #pragma unroll
    for (int s = 128; s > 0; s >>= 1) {
        if (t < s) red[t] += red[t + s];
        __syncthreads();
    }
    // band_mses = band_sums / (N*C*H*W); weights already folded into wmap
    if (t == 0) out[0] = red[0] * (1.0f / 25165824.0f);
}

extern "C" void kernel_launch(void* const* d_in, const int* in_sizes, int n_in,
                              void* d_out, int out_size, void* d_ws, size_t ws_size,
                              hipStream_t stream) {
    const float* pred  = (const float*)d_in[0];
    const float* gt    = (const float*)d_in[1];
    const float* bw    = (const float*)d_in[2];
    const float* masks = (const float*)d_in[3];
    float* out = (float*)d_out;

    char* ws = (char*)d_ws;
    float*  wmap     = (float*)ws;                       // 1 MiB
    float*  partials = (float*)(ws + (1 << 20));         // 96*512*4 = 192 KiB
    float2* fdata    = (float2*)(ws + (1 << 20) + (256 << 10));
    const size_t fixed = (1 << 20) + (256 << 10);
    const size_t img_bytes = (size_t)HW * HW * sizeof(float2);  // 2 MiB

    int chunk = 1;
    if (ws_size > fixed + img_bytes)
        chunk = (int)((ws_size - fixed) / img_bytes);
    if (chunk > NIMG) chunk = NIMG;
    if (chunk < 1) chunk = 1;

    wmap_kernel<<<(HW * HW + 255) / 256, 256, 0, stream>>>(bw, masks, wmap);

    for (int img0 = 0; img0 < NIMG; img0 += chunk) {
        int n = NIMG - img0 < chunk ? NIMG - img0 : chunk;
        dim3 grid(HW, n);
        rowfft_kernel<<<grid, 256, 0, stream>>>(pred, gt, fdata, img0);
        colfft_kernel<<<grid, 256, 0, stream>>>(fdata, wmap, partials, img0);
    }

    final_reduce<<<1, 256, 0, stream>>>(partials, out);
}

// Round 2
// 133.134 us; speedup vs baseline: 3.0724x; 3.0724x over previous
//
#include <hip/hip_runtime.h>
#include <math.h>

#define HW 512
#define LOG2HW 9
#define NIMG 96       // N*C = 32*3
#define NBANDS 16
#define NCOL 257      // rfft columns 0..256
#define ZPAD 514      // padded float2 row stride for rowfft LDS (512+2)
#define PI_F 3.14159265358979323846f

__device__ __forceinline__ unsigned bitrev9(unsigned x) {
    return __brev(x) >> (32 - LOG2HW);
}

// ---------- weight precompute ----------
// wmapk[k1*512+k2] = sum_b bw[b] * mask[b][(k1+256)%512][(k2+256)%512]
// (unshifted FFT frequency coordinates; absorbs fftshift)
__global__ void wmapk_kernel(const float* __restrict__ bw,
                             const float* __restrict__ masks,
                             float* __restrict__ wmapk) {
    int idx = blockIdx.x * 256 + threadIdx.x;        // k1*512 + k2
    int k1 = idx >> LOG2HW, k2 = idx & (HW - 1);
    int p1 = (k1 + HW / 2) & (HW - 1);
    int p2 = (k2 + HW / 2) & (HW - 1);
    int off = p1 * HW + p2;
    float s = 0.f;
    #pragma unroll
    for (int b = 0; b < NBANDS; ++b)
        s += bw[b] * masks[b * HW * HW + off];
    wmapk[idx] = s;
}

// wfold_br[c*512 + j] : folded Hermitian weight for column c at
// bit-reversed row index j (k1 = bitrev(j)).
// c in 1..255 folds partner (512-k1, 512-c); c==0 / c==256 are self-columns.
__global__ void wfold_kernel(const float* __restrict__ wmapk,
                             float* __restrict__ wfold_br) {
    int idx = blockIdx.x * 256 + threadIdx.x;        // c*512 + j
    if (idx >= NCOL * HW) return;
    int c = idx >> LOG2HW, j = idx & (HW - 1);
    int k1 = bitrev9(j);
    float s = wmapk[k1 * HW + c];
    if (c >= 1 && c <= 255)
        s += wmapk[((HW - k1) & (HW - 1)) * HW + (HW - c)];
    wfold_br[idx] = s;
}

// ---------- row pass ----------
// One block = 16 consecutive rows of one image, packed as 8 complex rows
// (even row -> real, odd row -> imag). 512-pt DIF FFT (natural in,
// bit-reversed out) on each. Unpack A(k),B(k) for k=0..256 and write
// TRANSPOSED: fdata[limg][k][row]  (so the column pass reads contiguous).
__global__ __launch_bounds__(256)
void rowfft_kernel(const float* __restrict__ pred,
                   const float* __restrict__ gt,
                   float2* __restrict__ fdata, int img0) {
    __shared__ float2 z[8 * ZPAD];
    const int limg = blockIdx.y;
    const int rg   = blockIdx.x;          // row group 0..31
    const int t    = threadIdx.x;
    const int img  = img0 + limg;
    const int r0   = rg * 16;

    const size_t gbase = ((size_t)img * HW + r0) * HW;
    const float4* p4 = (const float4*)(pred + gbase);
    const float4* g4 = (const float4*)(gt + gbase);

    // load 16 rows as 8 packed complex rows
    #pragma unroll
    for (int it = 0; it < 4; ++it) {
        int cg = t + it * 256;            // col-group 0..1023
        int j  = cg >> 7;                 // packed fft 0..7
        int cc = cg & 127;                // float4 column group
        float4 ae = p4[(2 * j) * 128 + cc];
        float4 be = g4[(2 * j) * 128 + cc];
        float4 ao = p4[(2 * j + 1) * 128 + cc];
        float4 bo = g4[(2 * j + 1) * 128 + cc];
        float2* dst = z + j * ZPAD + cc * 4;
        dst[0] = make_float2(ae.x - be.x, ao.x - bo.x);
        dst[1] = make_float2(ae.y - be.y, ao.y - bo.y);
        dst[2] = make_float2(ae.z - be.z, ao.z - bo.z);
        dst[3] = make_float2(ae.w - be.w, ao.w - bo.w);
    }
    __syncthreads();

    // 8 x 512-pt DIF FFT; thread t = butterfly t of every fft; twiddle
    // depends only on (t, stage) so one sincos serves all 8 ffts.
    #pragma unroll
    for (int lg = LOG2HW - 1; lg >= 0; --lg) {
        const int half = 1 << lg;
        const int pos  = t & (half - 1);
        const int i1   = ((t >> lg) << (lg + 1)) + pos;
        const int i2   = i1 + half;
        float sn, cs;
        __sincosf(-PI_F * (float)pos / (float)half, &sn, &cs);
        #pragma unroll
        for (int f = 0; f < 8; ++f) {
            float2* zz = z + f * ZPAD;
            float2 u = zz[i1], v = zz[i2];
            zz[i1] = make_float2(u.x + v.x, u.y + v.y);
            float dr = u.x - v.x, di = u.y - v.y;
            zz[i2] = make_float2(cs * dr - sn * di, cs * di + sn * dr);
        }
        __syncthreads();
    }

    // unpack + transposed write. lane group: k = kb + t/16, local row = t%16.
    float2* out = fdata + (size_t)limg * NCOL * HW + r0;
    const int klocal = t >> 4;
    const int rl     = t & 15;
    const int j      = rl >> 1;
    const int parity = rl & 1;
    #pragma unroll
    for (int kb = 0; kb <= 256; kb += 16) {
        int k = kb + klocal;
        if (k <= 256) {
            int bk  = bitrev9((unsigned)k & (HW - 1));
            int bnk = bitrev9((unsigned)(HW - k) & (HW - 1));
            float2 Zk = z[j * ZPAD + bk];
            float2 Zn = z[j * ZPAD + bnk];
            float2 v;
            if (parity == 0) {   // A(k) = (Z(k)+conj(Z(N-k)))/2
                v = make_float2(0.5f * (Zk.x + Zn.x), 0.5f * (Zk.y - Zn.y));
            } else {             // B(k) = (Z(k)-conj(Z(N-k)))/(2i)
                v = make_float2(0.5f * (Zk.y + Zn.y), 0.5f * (Zn.x - Zk.x));
            }
            out[(size_t)k * HW + rl] = v;
        }
    }
}

// ---------- column pass ----------
// One block per (image-in-chunk, rfft column c). Contiguous 4KB read,
// 512-pt DIF FFT, weighted power sum with bit-reversed folded weights.
__global__ __launch_bounds__(256)
void colfft_kernel(const float2* __restrict__ fdata,
                   const float* __restrict__ wfold_br,
                   float* __restrict__ partials, int img0) {
    __shared__ float2 z[HW];
    __shared__ float red[256];
    const int limg = blockIdx.y;
    const int c    = blockIdx.x;          // 0..256
    const int t    = threadIdx.x;

    const float2* in = fdata + ((size_t)limg * NCOL + c) * HW;
    z[t]       = in[t];
    z[t + 256] = in[t + 256];
    __syncthreads();

    #pragma unroll
    for (int lg = LOG2HW - 1; lg >= 0; --lg) {
        const int half = 1 << lg;
        const int pos  = t & (half - 1);
        const int i1   = ((t >> lg) << (lg + 1)) + pos;
        const int i2   = i1 + half;
        float sn, cs;
        __sincosf(-PI_F * (float)pos / (float)half, &sn, &cs);
        float2 u = z[i1], v = z[i2];
        z[i1] = make_float2(u.x + v.x, u.y + v.y);
        float dr = u.x - v.x, di = u.y - v.y;
        z[i2] = make_float2(cs * dr - sn * di, cs * di + sn * dr);
        __syncthreads();
    }

    const float* w = wfold_br + (size_t)c * HW;
    float acc = 0.f;
    #pragma unroll
    for (int it = 0; it < 2; ++it) {
        int i = t + it * 256;
        float2 v = z[i];
        acc += (v.x * v.x + v.y * v.y) * w[i];
    }
    red[t] = acc * (1.0f / (512.0f * 512.0f));   // ortho norm |F|^2 / 512^2
    __syncthreads();
    #pragma unroll
    for (int s = 128; s > 0; s >>= 1) {
        if (t < s) red[t] += red[t + s];
        __syncthreads();
    }
    if (t == 0)
        partials[(size_t)(img0 + limg) * NCOL + c] = red[0];
}

__global__ void final_reduce(const float* __restrict__ partials,
                             float* __restrict__ out) {
    __shared__ float red[256];
    const int t = threadIdx.x;
    float acc = 0.f;
    for (int i = t; i < NIMG * NCOL; i += 256) acc += partials[i];
    red[t] = acc;
    __syncthreads();
    #pragma unroll
    for (int s = 128; s > 0; s >>= 1) {
        if (t < s) red[t] += red[t + s];
        __syncthreads();
    }
    if (t == 0) out[0] = red[0] * (1.0f / 25165824.0f);  // / (N*C*H*W)
}

extern "C" void kernel_launch(void* const* d_in, const int* in_sizes, int n_in,
                              void* d_out, int out_size, void* d_ws, size_t ws_size,
                              hipStream_t stream) {
    const float* pred  = (const float*)d_in[0];
    const float* gt    = (const float*)d_in[1];
    const float* bw    = (const float*)d_in[2];
    const float* masks = (const float*)d_in[3];
    float* out = (float*)d_out;

    char* ws = (char*)d_ws;
    float* wmapk    = (float*)ws;                          // 1 MiB
    float* wfold_br = (float*)(ws + (1 << 20));            // 526,336 B
    float* partials = (float*)(ws + (1 << 20) + (576 << 10)); // 98,688 B
    float2* fdata   = (float2*)(ws + (2 << 20));
    const size_t fixed = (2 << 20);
    const size_t img_bytes = (size_t)NCOL * HW * sizeof(float2);  // ~1.004 MiB

    int chunk = 1;
    if (ws_size > fixed + img_bytes)
        chunk = (int)((ws_size - fixed) / img_bytes);
    if (chunk > NIMG) chunk = NIMG;
    if (chunk < 1) chunk = 1;

    wmapk_kernel<<<(HW * HW) / 256, 256, 0, stream>>>(bw, masks, wmapk);
    wfold_kernel<<<(NCOL * HW + 255) / 256, 256, 0, stream>>>(wmapk, wfold_br);

    for (int img0 = 0; img0 < NIMG; img0 += chunk) {
        int n = NIMG - img0 < chunk ? NIMG - img0 : chunk;
        rowfft_kernel<<<dim3(HW / 16, n), 256, 0, stream>>>(pred, gt, fdata, img0);
        colfft_kernel<<<dim3(NCOL, n), 256, 0, stream>>>(fdata, wfold_br, partials, img0);
    }

    final_reduce<<<1, 256, 0, stream>>>(partials, out);
}

// Round 3
// 116.510 us; speedup vs baseline: 3.5107x; 1.1427x over previous
//
#include <hip/hip_runtime.h>
#include <math.h>

#define HW 512
#define LOG2HW 9
#define NIMG 96       // N*C = 32*3
#define NBANDS 16
#define NCOL 257      // rfft columns 0..256
#define PSTRIDE 516   // float2 stride per FFT pack in LDS (bank-offsets packs)
#define PI_F 3.14159265358979323846f

// ---------- small complex helpers ----------
__device__ __forceinline__ float2 cadd(float2 a, float2 b){return make_float2(a.x+b.x, a.y+b.y);}
__device__ __forceinline__ float2 csub(float2 a, float2 b){return make_float2(a.x-b.x, a.y-b.y);}
__device__ __forceinline__ float2 cmul(float2 a, float2 b){return make_float2(a.x*b.x - a.y*b.y, a.x*b.y + a.y*b.x);}
__device__ __forceinline__ float2 mul_negi(float2 a){return make_float2(a.y, -a.x);}  // a * (-i)

// octal digit reversal of 9-bit index (involution)
__device__ __forceinline__ int dr9(int p) {
    return ((p & 7) << 6) | (p & 56) | ((p >> 6) & 7);
}

// LDS physical address swizzle: conflict-free pass A, 4-way (b64 floor) B/C
__device__ __forceinline__ int phys(int i) {
    return i ^ (((i >> 6) & 7) << 1) ^ ((i >> 5) & 1);
}

// 8-point DFT, W8 = e^{-2*pi*i/8}: v[s] = sum_e u[e] * W8^{s*e}
__device__ __forceinline__ void dft8(const float2 u[8], float2 v[8]) {
    const float R = 0.70710678118654752440f;
    // evens -> E
    float2 s0 = cadd(u[0], u[4]), s1 = cadd(u[2], u[6]);
    float2 d0 = csub(u[0], u[4]), d1 = csub(u[2], u[6]);
    float2 E0 = cadd(s0, s1), E2 = csub(s0, s1);
    float2 ni = mul_negi(d1);
    float2 E1 = cadd(d0, ni), E3 = csub(d0, ni);
    // odds -> O
    float2 t0 = cadd(u[1], u[5]), t1 = cadd(u[3], u[7]);
    float2 e0 = csub(u[1], u[5]), e1 = csub(u[3], u[7]);
    float2 O0 = cadd(t0, t1), O2 = csub(t0, t1);
    float2 mi = mul_negi(e1);
    float2 O1 = cadd(e0, mi), O3 = csub(e0, mi);
    // twiddled odds: W8^1 = R(1-i), W8^2 = -i, W8^3 = -R(1+i)
    float2 w1O = make_float2(R * (O1.x + O1.y), R * (O1.y - O1.x));
    float2 w2O = mul_negi(O2);
    float2 w3O = make_float2(R * (O3.y - O3.x), -R * (O3.x + O3.y));
    v[0] = cadd(E0, O0);  v[4] = csub(E0, O0);
    v[1] = cadd(E1, w1O); v[5] = csub(E1, w1O);
    v[2] = cadd(E2, w2O); v[6] = csub(E2, w2O);
    v[3] = cadd(E3, w3O); v[7] = csub(E3, w3O);
}

// multiply v[s] by w^s, w = e^{i*ang}
__device__ __forceinline__ void twiddle_mul(float2 v[8], float ang) {
    float sn, cs;
    __sincosf(ang, &sn, &cs);
    float2 w1 = make_float2(cs, sn);
    float2 w2 = cmul(w1, w1), w3 = cmul(w2, w1), w4 = cmul(w2, w2);
    float2 w5 = cmul(w3, w2), w6 = cmul(w3, w3), w7 = cmul(w4, w3);
    v[1] = cmul(v[1], w1); v[2] = cmul(v[2], w2); v[3] = cmul(v[3], w3);
    v[4] = cmul(v[4], w4); v[5] = cmul(v[5], w5); v[6] = cmul(v[6], w6);
    v[7] = cmul(v[7], w7);
}

// 512-pt DIF radix-8 FFT core for one pack (64 threads = 1 wave, lane j).
// Input: u[] holds x[j + 64e]. Output: v[s] = X[dr9(8j+s)] (digit-reversed).
// Uses zz (PSTRIDE float2) as scratch; leaves pass-C result only in regs.
__device__ __forceinline__ void fft512_core(float2* zz, float2 u[8], float2 v[8], int j) {
    dft8(u, v);
    twiddle_mul(v, -(2.0f * PI_F / 512.0f) * (float)j);
    #pragma unroll
    for (int s = 0; s < 8; ++s) zz[phys(j + 64 * s)] = v[s];
    __syncthreads();
    const int sb = j >> 3, r = j & 7;
    #pragma unroll
    for (int e = 0; e < 8; ++e) u[e] = zz[phys(64 * sb + r + 8 * e)];
    dft8(u, v);
    twiddle_mul(v, -(2.0f * PI_F / 64.0f) * (float)r);
    #pragma unroll
    for (int s = 0; s < 8; ++s) zz[phys(64 * sb + r + 8 * s)] = v[s];
    __syncthreads();
    #pragma unroll
    for (int e = 0; e < 8; ++e) u[e] = zz[phys(8 * j + e)];
    dft8(u, v);
}

// ---------- weight precompute ----------
// wmapk[k1*512+k2] = sum_b bw[b]*mask[b][(k1+256)%512][(k2+256)%512]
__global__ void wmapk_kernel(const float* __restrict__ bw,
                             const float* __restrict__ masks,
                             float* __restrict__ wmapk) {
    int idx = blockIdx.x * 256 + threadIdx.x;
    int k1 = idx >> LOG2HW, k2 = idx & (HW - 1);
    int p1 = (k1 + HW / 2) & (HW - 1);
    int p2 = (k2 + HW / 2) & (HW - 1);
    int off = p1 * HW + p2;
    float s = 0.f;
    #pragma unroll
    for (int b = 0; b < NBANDS; ++b)
        s += bw[b] * masks[b * HW * HW + off];
    wmapk[idx] = s;
}

// wfold_dr[c*512 + p]: Hermitian-folded weight for column c at storage
// position p (k1 = dr9(p)); includes ortho norm 1/512^2.
__global__ void wfold_kernel(const float* __restrict__ wmapk,
                             float* __restrict__ wfold_dr) {
    int idx = blockIdx.x * 256 + threadIdx.x;
    if (idx >= NCOL * HW) return;
    int c = idx >> LOG2HW, p = idx & (HW - 1);
    int k1 = dr9(p);
    float s = wmapk[k1 * HW + c];
    if (c >= 1 && c <= 255)
        s += wmapk[((HW - k1) & (HW - 1)) * HW + (HW - c)];
    wfold_dr[idx] = s * (1.0f / (512.0f * 512.0f));
}

// ---------- row pass ----------
// Block = 8 consecutive rows of one image = 4 packed complex FFTs
// (wave f: rows 2f (real) / 2f+1 (imag)). Writes A(k),B(k) for k=0..256
// transposed: fdata[limg][k][row].
__global__ __launch_bounds__(256)
void rowfft_kernel(const float* __restrict__ pred,
                   const float* __restrict__ gt,
                   float2* __restrict__ fdata, int img0) {
    __shared__ float2 z[4 * PSTRIDE];
    const int limg = blockIdx.y;
    const int t = threadIdx.x;
    const int f = t >> 6;          // pack / wave 0..3
    const int j = t & 63;
    const int img = img0 + limg;
    const int r0 = blockIdx.x * 8;

    const float* pA = pred + ((size_t)img * HW + r0 + 2 * f) * HW;
    const float* gA = gt   + ((size_t)img * HW + r0 + 2 * f) * HW;
    const float* pB = pA + HW;
    const float* gB = gA + HW;
    float2* zz = z + f * PSTRIDE;

    float2 u[8], v[8];
    #pragma unroll
    for (int e = 0; e < 8; ++e) {
        int i = j + 64 * e;
        u[e] = make_float2(pA[i] - gA[i], pB[i] - gB[i]);
    }
    fft512_core(zz, u, v, j);

    // store pass-C result (digit-reversed Z) for cross-lane unpack
    #pragma unroll
    for (int s = 0; s < 8; ++s) zz[phys(8 * j + s)] = v[s];
    __syncthreads();

    // unpack: thread -> (k group, local row rl); row r0+rl, pack fp=rl/2
    const int klocal = t >> 3;     // 0..31
    const int rl = t & 7;
    const int fp = rl >> 1, parity = rl & 1;
    const float2* zf = z + fp * PSTRIDE;
    float2* outbase = fdata + (size_t)limg * NCOL * HW + r0;
    #pragma unroll
    for (int kb = 0; kb < 9; ++kb) {
        int k = kb * 32 + klocal;
        if (k <= 256) {
            float2 Zk = zf[phys(dr9(k))];
            float2 Zn = zf[phys(dr9((HW - k) & (HW - 1)))];
            float2 o;
            if (parity == 0) {   // A(k) = (Z(k)+conj(Z(N-k)))/2
                o = make_float2(0.5f * (Zk.x + Zn.x), 0.5f * (Zk.y - Zn.y));
            } else {             // B(k) = (Z(k)-conj(Z(N-k)))/(2i)
                o = make_float2(0.5f * (Zk.y + Zn.y), 0.5f * (Zn.x - Zk.x));
            }
            outbase[(size_t)k * HW + rl] = o;
        }
    }
}

// ---------- column pass ----------
// Block = 4 columns (one wave each) of one image. Column FFT + weighted
// power, wave-level shuffle reduction, one partial per column.
__global__ __launch_bounds__(256)
void colfft_kernel(const float2* __restrict__ fdata,
                   const float* __restrict__ wfold_dr,
                   float* __restrict__ partials, int img0) {
    __shared__ float2 z[4 * PSTRIDE];
    const int limg = blockIdx.y;
    const int t = threadIdx.x;
    const int wv = t >> 6, j = t & 63;
    const int c = blockIdx.x * 4 + wv;            // 0..259
    const int cl = c > 256 ? 256 : c;             // clamp for loads

    const float2* in = fdata + ((size_t)limg * NCOL + cl) * HW;
    float2* zz = z + wv * PSTRIDE;

    float2 u[8], v[8];
    #pragma unroll
    for (int e = 0; e < 8; ++e) u[e] = in[j + 64 * e];
    fft512_core(zz, u, v, j);

    // weighted power from regs; storage position p = 8j+s
    const float4* w4 = (const float4*)(wfold_dr + (size_t)cl * HW + 8 * j);
    float4 wa = w4[0], wb = w4[1];
    float acc = 0.f;
    acc += (v[0].x*v[0].x + v[0].y*v[0].y) * wa.x;
    acc += (v[1].x*v[1].x + v[1].y*v[1].y) * wa.y;
    acc += (v[2].x*v[2].x + v[2].y*v[2].y) * wa.z;
    acc += (v[3].x*v[3].x + v[3].y*v[3].y) * wa.w;
    acc += (v[4].x*v[4].x + v[4].y*v[4].y) * wb.x;
    acc += (v[5].x*v[5].x + v[5].y*v[5].y) * wb.y;
    acc += (v[6].x*v[6].x + v[6].y*v[6].y) * wb.z;
    acc += (v[7].x*v[7].x + v[7].y*v[7].y) * wb.w;

    #pragma unroll
    for (int off = 32; off > 0; off >>= 1)
        acc += __shfl_down(acc, off, 64);
    if (j == 0 && c <= 256)
        partials[(size_t)(img0 + limg) * NCOL + c] = acc;
}

__global__ void final_reduce(const float* __restrict__ partials,
                             float* __restrict__ out) {
    __shared__ float red[256];
    const int t = threadIdx.x;
    float acc = 0.f;
    for (int i = t; i < NIMG * NCOL; i += 256) acc += partials[i];
    red[t] = acc;
    __syncthreads();
    #pragma unroll
    for (int s = 128; s > 0; s >>= 1) {
        if (t < s) red[t] += red[t + s];
        __syncthreads();
    }
    if (t == 0) out[0] = red[0] * (1.0f / 25165824.0f);  // / (N*C*H*W)
}

extern "C" void kernel_launch(void* const* d_in, const int* in_sizes, int n_in,
                              void* d_out, int out_size, void* d_ws, size_t ws_size,
                              hipStream_t stream) {
    const float* pred  = (const float*)d_in[0];
    const float* gt    = (const float*)d_in[1];
    const float* bw    = (const float*)d_in[2];
    const float* masks = (const float*)d_in[3];
    float* out = (float*)d_out;

    char* ws = (char*)d_ws;
    float* wmapk    = (float*)ws;                             // 1 MiB
    float* wfold_dr = (float*)(ws + (1 << 20));               // 526,336 B
    float* partials = (float*)(ws + (1 << 20) + (576 << 10)); // 98,688 B
    float2* fdata   = (float2*)(ws + (2 << 20));
    const size_t fixed = (2 << 20);
    const size_t img_bytes = (size_t)NCOL * HW * sizeof(float2);  // ~1.004 MiB

    int chunk = 1;
    if (ws_size > fixed + img_bytes)
        chunk = (int)((ws_size - fixed) / img_bytes);
    if (chunk > NIMG) chunk = NIMG;
    if (chunk < 1) chunk = 1;

    wmapk_kernel<<<(HW * HW) / 256, 256, 0, stream>>>(bw, masks, wmapk);
    wfold_kernel<<<(NCOL * HW + 255) / 256, 256, 0, stream>>>(wmapk, wfold_dr);

    for (int img0 = 0; img0 < NIMG; img0 += chunk) {
        int n = NIMG - img0 < chunk ? NIMG - img0 : chunk;
        rowfft_kernel<<<dim3(HW / 8, n), 256, 0, stream>>>(pred, gt, fdata, img0);
        colfft_kernel<<<dim3((NCOL + 3) / 4, n), 256, 0, stream>>>(fdata, wfold_dr, partials, img0);
    }

    final_reduce<<<1, 256, 0, stream>>>(partials, out);
}

// Round 4
// 107.928 us; speedup vs baseline: 3.7899x; 1.0795x over previous
//
#include <hip/hip_runtime.h>
#include <math.h>

#define HW 512
#define LOG2HW 9
#define NIMG 96       // N*C = 32*3
#define NBANDS 16
#define NCOL 257      // rfft columns 0..256
#define PSTRIDE 518   // float2 stride per FFT pack in LDS (bank-offsets packs)
#define PI_F 3.14159265358979323846f

// ---------- small complex helpers ----------
__device__ __forceinline__ float2 cadd(float2 a, float2 b){return make_float2(a.x+b.x, a.y+b.y);}
__device__ __forceinline__ float2 csub(float2 a, float2 b){return make_float2(a.x-b.x, a.y-b.y);}
__device__ __forceinline__ float2 cmul(float2 a, float2 b){return make_float2(a.x*b.x - a.y*b.y, a.x*b.y + a.y*b.x);}
__device__ __forceinline__ float2 mul_negi(float2 a){return make_float2(a.y, -a.x);}  // a * (-i)

// octal digit reversal of 9-bit index (involution)
__device__ __forceinline__ int dr9(int p) {
    return ((p & 7) << 6) | (p & 56) | ((p >> 6) & 7);
}

// LDS logical->physical swizzle (involution). Preserves bits 0-1 so
// 4-element float2 runs stay contiguous (float4-storable).
__device__ __forceinline__ int swz(int i) {
    return i ^ (((i >> 6) & 7) << 2);
}

// 8-point DFT, W8 = e^{-2*pi*i/8}: v[s] = sum_e u[e] * W8^{s*e}
__device__ __forceinline__ void dft8(const float2 u[8], float2 v[8]) {
    const float R = 0.70710678118654752440f;
    float2 s0 = cadd(u[0], u[4]), s1 = cadd(u[2], u[6]);
    float2 d0 = csub(u[0], u[4]), d1 = csub(u[2], u[6]);
    float2 E0 = cadd(s0, s1), E2 = csub(s0, s1);
    float2 ni = mul_negi(d1);
    float2 E1 = cadd(d0, ni), E3 = csub(d0, ni);
    float2 t0 = cadd(u[1], u[5]), t1 = cadd(u[3], u[7]);
    float2 e0 = csub(u[1], u[5]), e1 = csub(u[3], u[7]);
    float2 O0 = cadd(t0, t1), O2 = csub(t0, t1);
    float2 mi = mul_negi(e1);
    float2 O1 = cadd(e0, mi), O3 = csub(e0, mi);
    float2 w1O = make_float2(R * (O1.x + O1.y), R * (O1.y - O1.x));
    float2 w2O = mul_negi(O2);
    float2 w3O = make_float2(R * (O3.y - O3.x), -R * (O3.x + O3.y));
    v[0] = cadd(E0, O0);  v[4] = csub(E0, O0);
    v[1] = cadd(E1, w1O); v[5] = csub(E1, w1O);
    v[2] = cadd(E2, w2O); v[6] = csub(E2, w2O);
    v[3] = cadd(E3, w3O); v[7] = csub(E3, w3O);
}

// multiply v[s] by w^s, w = e^{i*ang}
__device__ __forceinline__ void twiddle_mul(float2 v[8], float ang) {
    float sn, cs;
    __sincosf(ang, &sn, &cs);
    float2 w1 = make_float2(cs, sn);
    float2 w2 = cmul(w1, w1), w3 = cmul(w2, w1), w4 = cmul(w2, w2);
    float2 w5 = cmul(w3, w2), w6 = cmul(w3, w3), w7 = cmul(w4, w3);
    v[1] = cmul(v[1], w1); v[2] = cmul(v[2], w2); v[3] = cmul(v[3], w3);
    v[4] = cmul(v[4], w4); v[5] = cmul(v[5], w5); v[6] = cmul(v[6], w6);
    v[7] = cmul(v[7], w7);
}

// 512-pt DIF radix-8 FFT, one pack per WAVE (lane j in 0..63).
// zz is this wave's private LDS slice -> all exchanges are intra-wave,
// NO workgroup barriers (wave-lockstep LDS + compiler lgkmcnt waits).
// Input: u[e] = x[j + 64e]. Output: v[s] = X[dr9(8j+s)].
__device__ __forceinline__ void fft512_wave(float2* zz, float2 u[8], float2 v[8], int j) {
    dft8(u, v);
    twiddle_mul(v, -(2.0f * PI_F / 512.0f) * (float)j);
    #pragma unroll
    for (int s = 0; s < 8; ++s) zz[swz(j + 64 * s)] = v[s];
    __builtin_amdgcn_wave_barrier();
    const int sb = j >> 3, r = j & 7;
    #pragma unroll
    for (int e = 0; e < 8; ++e) u[e] = zz[swz(64 * sb + r + 8 * e)];
    __builtin_amdgcn_wave_barrier();
    dft8(u, v);
    twiddle_mul(v, -(2.0f * PI_F / 64.0f) * (float)r);
    #pragma unroll
    for (int s = 0; s < 8; ++s) zz[swz(64 * sb + r + 8 * s)] = v[s];
    __builtin_amdgcn_wave_barrier();
    #pragma unroll
    for (int e = 0; e < 8; ++e) u[e] = zz[swz(8 * j + e)];
    __builtin_amdgcn_wave_barrier();
    dft8(u, v);
}

// ---------- weight precompute ----------
// wmapk[k1*512+k2] = sum_b bw[b]*mask[b][(k1+256)%512][(k2+256)%512]
__global__ void wmapk_kernel(const float* __restrict__ bw,
                             const float* __restrict__ masks,
                             float* __restrict__ wmapk) {
    int idx = blockIdx.x * 256 + threadIdx.x;
    int k1 = idx >> LOG2HW, k2 = idx & (HW - 1);
    int p1 = (k1 + HW / 2) & (HW - 1);
    int p2 = (k2 + HW / 2) & (HW - 1);
    int off = p1 * HW + p2;
    float s = 0.f;
    #pragma unroll
    for (int b = 0; b < NBANDS; ++b)
        s += bw[b] * masks[b * HW * HW + off];
    wmapk[idx] = s;
}

// wfold_dr[c*512 + p]: Hermitian-folded weight for column c at storage
// position p (k1 = dr9(p)); includes ortho norm 1/512^2.
__global__ void wfold_kernel(const float* __restrict__ wmapk,
                             float* __restrict__ wfold_dr) {
    int idx = blockIdx.x * 256 + threadIdx.x;
    if (idx >= NCOL * HW) return;
    int c = idx >> LOG2HW, p = idx & (HW - 1);
    int k1 = dr9(p);
    float s = wmapk[k1 * HW + c];
    if (c >= 1 && c <= 255)
        s += wmapk[((HW - k1) & (HW - 1)) * HW + (HW - c)];
    wfold_dr[idx] = s * (1.0f / (512.0f * 512.0f));
}

// ---------- row pass ----------
// Block = 16 consecutive rows of one image = 8 packed complex FFTs,
// wave f owns pack f (rows 2f: real, 2f+1: imag). float4 global loads,
// barrier-free wave-private FFT, pass-C stored at natural k, single
// __syncthreads, then cross-wave unpack writing 128 B row segments.
__global__ __launch_bounds__(512, 4)
void rowfft_kernel(const float* __restrict__ pred,
                   const float* __restrict__ gt,
                   float2* __restrict__ fdata, int img0) {
    __shared__ float2 z[8 * PSTRIDE];
    const int limg = blockIdx.y;
    const int t = threadIdx.x;
    const int f = t >> 6;          // pack / wave 0..7
    const int j = t & 63;
    const int img = img0 + limg;
    const int r0 = blockIdx.x * 16;

    float2* zz = z + f * PSTRIDE;
    const size_t rbase = ((size_t)img * HW + (r0 + 2 * f)) * HW;
    const float4* pA = (const float4*)(pred + rbase);
    const float4* gA = (const float4*)(gt + rbase);
    const float4* pB = (const float4*)(pred + rbase + HW);
    const float4* gB = (const float4*)(gt + rbase + HW);

    // phase 1: coalesced float4 loads -> packed err (re=rowA, im=rowB) in LDS
    #pragma unroll
    for (int it = 0; it < 2; ++it) {
        int c = j + 64 * it;                 // float4 chunk 0..127
        float4 a = pA[c], b = gA[c], d = pB[c], e = gB[c];
        float4* dst = (float4*)(zz + swz(4 * c));  // swz keeps 4-runs contiguous
        dst[0] = make_float4(a.x - b.x, d.x - e.x, a.y - b.y, d.y - e.y);
        dst[1] = make_float4(a.z - b.z, d.z - e.z, a.w - b.w, d.w - e.w);
    }
    __builtin_amdgcn_wave_barrier();

    float2 u[8], v[8];
    #pragma unroll
    for (int e = 0; e < 8; ++e) u[e] = zz[swz(j + 64 * e)];
    __builtin_amdgcn_wave_barrier();
    fft512_wave(zz, u, v, j);
    __builtin_amdgcn_wave_barrier();

    // pass-C result stored at natural frequency index k = dr9(8j+s)
    const int m = 8 * (j & 7) + (j >> 3);
    #pragma unroll
    for (int s = 0; s < 8; ++s) zz[swz(64 * s + m)] = v[s];
    __syncthreads();

    // unpack: thread -> (klocal = t>>4, rl = t&15); 16 consecutive rl
    // write one contiguous 128 B segment of row k.
    const int klocal = t >> 4;     // 0..31
    const int rl = t & 15;
    const int fp = rl >> 1, parity = rl & 1;
    const float2* zf = z + fp * PSTRIDE;
    float2* outbase = fdata + (size_t)limg * NCOL * HW + r0;
    #pragma unroll
    for (int kb = 0; kb < 9; ++kb) {
        int k = kb * 32 + klocal;
        if (k <= 256) {
            float2 Zk = zf[swz(k)];
            float2 Zn = zf[swz((HW - k) & (HW - 1))];
            float2 o;
            if (parity == 0) {   // A(k) = (Z(k)+conj(Z(N-k)))/2
                o = make_float2(0.5f * (Zk.x + Zn.x), 0.5f * (Zk.y - Zn.y));
            } else {             // B(k) = (Z(k)-conj(Z(N-k)))/(2i)
                o = make_float2(0.5f * (Zk.y + Zn.y), 0.5f * (Zn.x - Zk.x));
            }
            outbase[(size_t)k * HW + rl] = o;
        }
    }
}

// ---------- column pass ----------
// Block = 4 columns (one wave each) of one image. Contiguous reads,
// barrier-free wave-private FFT, weighted power + shfl reduce.
__global__ __launch_bounds__(256)
void colfft_kernel(const float2* __restrict__ fdata,
                   const float* __restrict__ wfold_dr,
                   float* __restrict__ partials, int img0) {
    __shared__ float2 z[4 * PSTRIDE];
    const int limg = blockIdx.y;
    const int t = threadIdx.x;
    const int wv = t >> 6, j = t & 63;
    const int c = blockIdx.x * 4 + wv;            // 0..259
    const int cl = c > 256 ? 256 : c;             // clamp for loads

    const float2* in = fdata + ((size_t)limg * NCOL + cl) * HW;
    float2* zz = z + wv * PSTRIDE;

    float2 u[8], v[8];
    #pragma unroll
    for (int e = 0; e < 8; ++e) u[e] = in[j + 64 * e];
    fft512_wave(zz, u, v, j);

    // weighted power from regs; storage position p = 8j+s
    const float4* w4 = (const float4*)(wfold_dr + (size_t)cl * HW + 8 * j);
    float4 wa = w4[0], wb = w4[1];
    float acc = 0.f;
    acc += (v[0].x*v[0].x + v[0].y*v[0].y) * wa.x;
    acc += (v[1].x*v[1].x + v[1].y*v[1].y) * wa.y;
    acc += (v[2].x*v[2].x + v[2].y*v[2].y) * wa.z;
    acc += (v[3].x*v[3].x + v[3].y*v[3].y) * wa.w;
    acc += (v[4].x*v[4].x + v[4].y*v[4].y) * wb.x;
    acc += (v[5].x*v[5].x + v[5].y*v[5].y) * wb.y;
    acc += (v[6].x*v[6].x + v[6].y*v[6].y) * wb.z;
    acc += (v[7].x*v[7].x + v[7].y*v[7].y) * wb.w;

    #pragma unroll
    for (int off = 32; off > 0; off >>= 1)
        acc += __shfl_down(acc, off, 64);
    if (j == 0 && c <= 256)
        partials[(size_t)(img0 + limg) * NCOL + c] = acc;
}

__global__ void final_reduce(const float* __restrict__ partials,
                             float* __restrict__ out) {
    __shared__ float red[256];
    const int t = threadIdx.x;
    float acc = 0.f;
    for (int i = t; i < NIMG * NCOL; i += 256) acc += partials[i];
    red[t] = acc;
    __syncthreads();
    #pragma unroll
    for (int s = 128; s > 0; s >>= 1) {
        if (t < s) red[t] += red[t + s];
        __syncthreads();
    }
    if (t == 0) out[0] = red[0] * (1.0f / 25165824.0f);  // / (N*C*H*W)
}

extern "C" void kernel_launch(void* const* d_in, const int* in_sizes, int n_in,
                              void* d_out, int out_size, void* d_ws, size_t ws_size,
                              hipStream_t stream) {
    const float* pred  = (const float*)d_in[0];
    const float* gt    = (const float*)d_in[1];
    const float* bw    = (const float*)d_in[2];
    const float* masks = (const float*)d_in[3];
    float* out = (float*)d_out;

    char* ws = (char*)d_ws;
    float* wmapk    = (float*)ws;                             // 1 MiB
    float* wfold_dr = (float*)(ws + (1 << 20));               // 526,336 B
    float* partials = (float*)(ws + (1 << 20) + (576 << 10)); // 98,688 B
    float2* fdata   = (float2*)(ws + (2 << 20));
    const size_t fixed = (2 << 20);
    const size_t img_bytes = (size_t)NCOL * HW * sizeof(float2);  // ~1.004 MiB

    int chunk = 1;
    if (ws_size > fixed + img_bytes)
        chunk = (int)((ws_size - fixed) / img_bytes);
    if (chunk > NIMG) chunk = NIMG;
    if (chunk < 1) chunk = 1;

    wmapk_kernel<<<(HW * HW) / 256, 256, 0, stream>>>(bw, masks, wmapk);
    wfold_kernel<<<(NCOL * HW + 255) / 256, 256, 0, stream>>>(wmapk, wfold_dr);

    for (int img0 = 0; img0 < NIMG; img0 += chunk) {
        int n = NIMG - img0 < chunk ? NIMG - img0 : chunk;
        rowfft_kernel<<<dim3(HW / 16, n), 512, 0, stream>>>(pred, gt, fdata, img0);
        colfft_kernel<<<dim3((NCOL + 3) / 4, n), 256, 0, stream>>>(fdata, wfold_dr, partials, img0);
    }

    final_reduce<<<1, 256, 0, stream>>>(partials, out);
}

// Round 5
// 96.638 us; speedup vs baseline: 4.2327x; 1.1168x over previous
//
#include <hip/hip_runtime.h>
#include <hip/hip_fp16.h>
#include <math.h>

#define HW 512
#define LOG2HW 9
#define NIMG 96       // N*C = 32*3
#define NBANDS 16
#define NCOL 257      // rfft columns 0..256
#define PSTRIDE 518   // float2 stride per FFT pack in LDS
#define IMG_H2 (17 * 16 * 16 * 32)   // half2 per image: [ct17][rt16][cl16][rl32]
#define PI_F 3.14159265358979323846f

// ---------- small complex helpers ----------
__device__ __forceinline__ float2 cadd(float2 a, float2 b){return make_float2(a.x+b.x, a.y+b.y);}
__device__ __forceinline__ float2 csub(float2 a, float2 b){return make_float2(a.x-b.x, a.y-b.y);}
__device__ __forceinline__ float2 cmul(float2 a, float2 b){return make_float2(a.x*b.x - a.y*b.y, a.x*b.y + a.y*b.x);}
__device__ __forceinline__ float2 mul_negi(float2 a){return make_float2(a.y, -a.x);}  // a * (-i)

// octal digit reversal of 9-bit index (involution)
__device__ __forceinline__ int dr9(int p) {
    return ((p & 7) << 6) | (p & 56) | ((p >> 6) & 7);
}

// LDS logical->physical swizzle (involution). Preserves bits 0-1 so
// 4-element float2 runs stay contiguous (float4-storable).
__device__ __forceinline__ int swz(int i) {
    return i ^ (((i >> 6) & 7) << 2);
}

// 8-point DFT, W8 = e^{-2*pi*i/8}: v[s] = sum_e u[e] * W8^{s*e}
__device__ __forceinline__ void dft8(const float2 u[8], float2 v[8]) {
    const float R = 0.70710678118654752440f;
    float2 s0 = cadd(u[0], u[4]), s1 = cadd(u[2], u[6]);
    float2 d0 = csub(u[0], u[4]), d1 = csub(u[2], u[6]);
    float2 E0 = cadd(s0, s1), E2 = csub(s0, s1);
    float2 ni = mul_negi(d1);
    float2 E1 = cadd(d0, ni), E3 = csub(d0, ni);
    float2 t0 = cadd(u[1], u[5]), t1 = cadd(u[3], u[7]);
    float2 e0 = csub(u[1], u[5]), e1 = csub(u[3], u[7]);
    float2 O0 = cadd(t0, t1), O2 = csub(t0, t1);
    float2 mi = mul_negi(e1);
    float2 O1 = cadd(e0, mi), O3 = csub(e0, mi);
    float2 w1O = make_float2(R * (O1.x + O1.y), R * (O1.y - O1.x));
    float2 w2O = mul_negi(O2);
    float2 w3O = make_float2(R * (O3.y - O3.x), -R * (O3.x + O3.y));
    v[0] = cadd(E0, O0);  v[4] = csub(E0, O0);
    v[1] = cadd(E1, w1O); v[5] = csub(E1, w1O);
    v[2] = cadd(E2, w2O); v[6] = csub(E2, w2O);
    v[3] = cadd(E3, w3O); v[7] = csub(E3, w3O);
}

// multiply v[s] by w^s, w = e^{i*ang}
__device__ __forceinline__ void twiddle_mul(float2 v[8], float ang) {
    float sn, cs;
    __sincosf(ang, &sn, &cs);
    float2 w1 = make_float2(cs, sn);
    float2 w2 = cmul(w1, w1), w3 = cmul(w2, w1), w4 = cmul(w2, w2);
    float2 w5 = cmul(w3, w2), w6 = cmul(w3, w3), w7 = cmul(w4, w3);
    v[1] = cmul(v[1], w1); v[2] = cmul(v[2], w2); v[3] = cmul(v[3], w3);
    v[4] = cmul(v[4], w4); v[5] = cmul(v[5], w5); v[6] = cmul(v[6], w6);
    v[7] = cmul(v[7], w7);
}

// 512-pt DIF radix-8 FFT, one pack per WAVE (lane j in 0..63).
// zz is this wave's private LDS slice -> all exchanges intra-wave, no
// workgroup barriers. Input: u[e] = x[j + 64e]. Output: v[s] = X[dr9(8j+s)].
__device__ __forceinline__ void fft512_wave(float2* zz, float2 u[8], float2 v[8], int j) {
    dft8(u, v);
    twiddle_mul(v, -(2.0f * PI_F / 512.0f) * (float)j);
    #pragma unroll
    for (int s = 0; s < 8; ++s) zz[swz(j + 64 * s)] = v[s];
    __builtin_amdgcn_wave_barrier();
    const int sb = j >> 3, r = j & 7;
    #pragma unroll
    for (int e = 0; e < 8; ++e) u[e] = zz[swz(64 * sb + r + 8 * e)];
    __builtin_amdgcn_wave_barrier();
    dft8(u, v);
    twiddle_mul(v, -(2.0f * PI_F / 64.0f) * (float)r);
    #pragma unroll
    for (int s = 0; s < 8; ++s) zz[swz(64 * sb + r + 8 * s)] = v[s];
    __builtin_amdgcn_wave_barrier();
    #pragma unroll
    for (int e = 0; e < 8; ++e) u[e] = zz[swz(8 * j + e)];
    __builtin_amdgcn_wave_barrier();
    dft8(u, v);
}

// ---------- weight precompute ----------
__global__ void wmapk_kernel(const float* __restrict__ bw,
                             const float* __restrict__ masks,
                             float* __restrict__ wmapk) {
    int idx = blockIdx.x * 256 + threadIdx.x;
    int k1 = idx >> LOG2HW, k2 = idx & (HW - 1);
    int p1 = (k1 + HW / 2) & (HW - 1);
    int p2 = (k2 + HW / 2) & (HW - 1);
    int off = p1 * HW + p2;
    float s = 0.f;
    #pragma unroll
    for (int b = 0; b < NBANDS; ++b)
        s += bw[b] * masks[b * HW * HW + off];
    wmapk[idx] = s;
}

// wfold_dr[c*512 + p]: Hermitian-folded weight for column c at storage
// position p (k1 = dr9(p)); includes ortho norm 1/512^2.
__global__ void wfold_kernel(const float* __restrict__ wmapk,
                             float* __restrict__ wfold_dr) {
    int idx = blockIdx.x * 256 + threadIdx.x;
    if (idx >= NCOL * HW) return;
    int c = idx >> LOG2HW, p = idx & (HW - 1);
    int k1 = dr9(p);
    float s = wmapk[k1 * HW + c];
    if (c >= 1 && c <= 255)
        s += wmapk[((HW - k1) & (HW - 1)) * HW + (HW - c)];
    wfold_dr[idx] = s * (1.0f / (512.0f * 512.0f));
}

// ---------- row pass ----------
// Block = 16 consecutive rows of one image = 8 packed complex FFTs,
// wave f owns pack f (rows 2f: real, 2f+1: imag). Pass-C stored at
// natural k, single __syncthreads, then cross-wave unpack writing
// half2 (f16 complex) into tiled layout [ct][rt][cl][rl] so both this
// kernel's stores and colfft's loads are contiguous runs.
__global__ __launch_bounds__(512, 4)
void rowfft_kernel(const float* __restrict__ pred,
                   const float* __restrict__ gt,
                   __half2* __restrict__ fdata, int img0) {
    __shared__ float2 z[8 * PSTRIDE];
    const int limg = blockIdx.y;
    const int t = threadIdx.x;
    const int f = t >> 6;          // pack / wave 0..7
    const int j = t & 63;
    const int img = img0 + limg;
    const int r0 = blockIdx.x * 16;

    float2* zz = z + f * PSTRIDE;
    const size_t rbase = ((size_t)img * HW + (r0 + 2 * f)) * HW;
    const float4* pA = (const float4*)(pred + rbase);
    const float4* gA = (const float4*)(gt + rbase);
    const float4* pB = (const float4*)(pred + rbase + HW);
    const float4* gB = (const float4*)(gt + rbase + HW);

    // coalesced float4 loads -> packed err (re=rowA, im=rowB) in LDS
    #pragma unroll
    for (int it = 0; it < 2; ++it) {
        int c = j + 64 * it;                 // float4 chunk 0..127
        float4 a = pA[c], b = gA[c], d = pB[c], e = gB[c];
        float4* dst = (float4*)(zz + swz(4 * c));
        dst[0] = make_float4(a.x - b.x, d.x - e.x, a.y - b.y, d.y - e.y);
        dst[1] = make_float4(a.z - b.z, d.z - e.z, a.w - b.w, d.w - e.w);
    }
    __builtin_amdgcn_wave_barrier();

    float2 u[8], v[8];
    #pragma unroll
    for (int e = 0; e < 8; ++e) u[e] = zz[swz(j + 64 * e)];
    __builtin_amdgcn_wave_barrier();
    fft512_wave(zz, u, v, j);
    __builtin_amdgcn_wave_barrier();

    // pass-C result stored at natural frequency index k = dr9(8j+s) = 64s+m
    const int m = 8 * (j & 7) + (j >> 3);
    #pragma unroll
    for (int s = 0; s < 8; ++s) zz[swz(64 * s + m)] = v[s];
    __syncthreads();

    // unpack: thread -> (cpos = t>>4, rl = t&15); row r0+rl holds
    // spectrum A (even rl) / B (odd rl) of pack fp = rl>>1.
    const int cpos = t >> 4;     // 0..31
    const int rl = t & 15;
    const int fp = rl >> 1, parity = rl & 1;
    const float2* zf = z + fp * PSTRIDE;
    const int rt = r0 >> 5;            // r-tile (32 rows)
    const int rlo = r0 & 31;           // 0 or 16
    __half2* img_base = fdata + (size_t)limg * IMG_H2;
    #pragma unroll
    for (int kb = 0; kb < 9; ++kb) {
        int c = kb * 32 + cpos;
        if (c <= 256) {
            float2 Zk = zf[swz(c)];
            float2 Zn = zf[swz((HW - c) & (HW - 1))];
            float2 o;
            if (parity == 0) {   // A(c) = (Z(c)+conj(Z(N-c)))/2
                o = make_float2(0.5f * (Zk.x + Zn.x), 0.5f * (Zk.y - Zn.y));
            } else {             // B(c) = (Z(c)-conj(Z(N-c)))/(2i)
                o = make_float2(0.5f * (Zk.y + Zn.y), 0.5f * (Zn.x - Zk.x));
            }
            int ct_ = c >> 4, cl_ = c & 15;
            img_base[(size_t)(((ct_ * 16 + rt) * 16 + cl_) * 32) + rlo + rl] =
                __floats2half2_rn(o.x, o.y);
        }
    }
}

// ---------- column pass ----------
// Block = 4 columns (one wave each). Tiled f16 reads (128 B runs),
// barrier-free wave-private FFT, weighted power + shfl reduce.
__global__ __launch_bounds__(256)
void colfft_kernel(const __half2* __restrict__ fdata,
                   const float* __restrict__ wfold_dr,
                   float* __restrict__ partials, int img0) {
    __shared__ float2 z[4 * PSTRIDE];
    const int limg = blockIdx.y;
    const int t = threadIdx.x;
    const int wv = t >> 6, j = t & 63;
    const int c = blockIdx.x * 4 + wv;            // 0..259
    const int cl_c = c > 256 ? 256 : c;           // clamp for loads

    const __half2* in = fdata + (size_t)limg * IMG_H2
                      + (size_t)((cl_c >> 4) * 8192 + (cl_c & 15) * 32);
    float2* zz = z + wv * PSTRIDE;

    float2 u[8], v[8];
    #pragma unroll
    for (int e = 0; e < 8; ++e) {
        int r = j + 64 * e;
        __half2 h = in[(r >> 5) * 512 + (r & 31)];
        u[e] = make_float2(__low2float(h), __high2float(h));
    }
    fft512_wave(zz, u, v, j);

    // weighted power from regs; storage position p = 8j+s
    const float4* w4 = (const float4*)(wfold_dr + (size_t)cl_c * HW + 8 * j);
    float4 wa = w4[0], wb = w4[1];
    float acc = 0.f;
    acc += (v[0].x*v[0].x + v[0].y*v[0].y) * wa.x;
    acc += (v[1].x*v[1].x + v[1].y*v[1].y) * wa.y;
    acc += (v[2].x*v[2].x + v[2].y*v[2].y) * wa.z;
    acc += (v[3].x*v[3].x + v[3].y*v[3].y) * wa.w;
    acc += (v[4].x*v[4].x + v[4].y*v[4].y) * wb.x;
    acc += (v[5].x*v[5].x + v[5].y*v[5].y) * wb.y;
    acc += (v[6].x*v[6].x + v[6].y*v[6].y) * wb.z;
    acc += (v[7].x*v[7].x + v[7].y*v[7].y) * wb.w;

    #pragma unroll
    for (int off = 32; off > 0; off >>= 1)
        acc += __shfl_down(acc, off, 64);
    if (j == 0 && c <= 256)
        partials[(size_t)(img0 + limg) * NCOL + c] = acc;
}

__global__ void final_reduce(const float* __restrict__ partials,
                             float* __restrict__ out) {
    __shared__ float red[256];
    const int t = threadIdx.x;
    float acc = 0.f;
    for (int i = t; i < NIMG * NCOL; i += 256) acc += partials[i];
    red[t] = acc;
    __syncthreads();
    #pragma unroll
    for (int s = 128; s > 0; s >>= 1) {
        if (t < s) red[t] += red[t + s];
        __syncthreads();
    }
    if (t == 0) out[0] = red[0] * (1.0f / 25165824.0f);  // / (N*C*H*W)
}

extern "C" void kernel_launch(void* const* d_in, const int* in_sizes, int n_in,
                              void* d_out, int out_size, void* d_ws, size_t ws_size,
                              hipStream_t stream) {
    const float* pred  = (const float*)d_in[0];
    const float* gt    = (const float*)d_in[1];
    const float* bw    = (const float*)d_in[2];
    const float* masks = (const float*)d_in[3];
    float* out = (float*)d_out;

    char* ws = (char*)d_ws;
    float* wmapk    = (float*)ws;                             // 1 MiB
    float* wfold_dr = (float*)(ws + (1 << 20));               // 526,336 B
    float* partials = (float*)(ws + (1 << 20) + (576 << 10)); // 98,688 B
    __half2* fdata  = (__half2*)(ws + (2 << 20));
    const size_t fixed = (2 << 20);
    const size_t img_bytes = (size_t)IMG_H2 * sizeof(__half2);  // 557,056 B

    int chunk = 1;
    if (ws_size > fixed + img_bytes)
        chunk = (int)((ws_size - fixed) / img_bytes);
    if (chunk > NIMG) chunk = NIMG;
    if (chunk < 1) chunk = 1;

    wmapk_kernel<<<(HW * HW) / 256, 256, 0, stream>>>(bw, masks, wmapk);
    wfold_kernel<<<(NCOL * HW + 255) / 256, 256, 0, stream>>>(wmapk, wfold_dr);

    for (int img0 = 0; img0 < NIMG; img0 += chunk) {
        int n = NIMG - img0 < chunk ? NIMG - img0 : chunk;
        rowfft_kernel<<<dim3(HW / 16, n), 512, 0, stream>>>(pred, gt, fdata, img0);
        colfft_kernel<<<dim3((NCOL + 3) / 4, n), 256, 0, stream>>>(fdata, wfold_dr, partials, img0);
    }

    final_reduce<<<1, 256, 0, stream>>>(partials, out);
}